// Round 7
// baseline (314.871 us; speedup 1.0000x reference)
//
#include <hip/hip_runtime.h>
#include <hip/hip_bf16.h>

typedef unsigned short u16;
using short8 = __attribute__((ext_vector_type(8))) short;
using f32x4  = __attribute__((ext_vector_type(4))) float;
using f32x16 = __attribute__((ext_vector_type(16))) float;

#define IN_FEAT  4096
#define OUT_FEAT 4096
#define BATCH    2048
// packed triangular B: group g (128 rows) has row length (g+1)*128 u16;
// group base = 16384 * g*(g+1)/2; total = 16384 * 528 u16 per matrix.
#define BPACK    8650752

// direct global->LDS, 16B per lane; LDS dest is wave-uniform base + lane*16
#define GLOAD16(gp, lp)                                                        \
    __builtin_amdgcn_global_load_lds(                                          \
        (__attribute__((address_space(1))) void*)(gp),                         \
        (__attribute__((address_space(3))) void*)(lp), 16, 0, 0)

// ---------------------------------------------------------------------------
// Kernel 1: split x (f32) into bf16 hi + lo residual. 16B/lane both ways.
// ---------------------------------------------------------------------------
__global__ __launch_bounds__(256) void split_x(const float* __restrict__ x,
                                               u16* __restrict__ xhi,
                                               u16* __restrict__ xlo)
{
    const int n8 = (BATCH * IN_FEAT) / 8;
    for (int i = blockIdx.x * blockDim.x + threadIdx.x; i < n8;
         i += gridDim.x * blockDim.x) {
        float4 a = ((const float4*)x)[2 * i];
        float4 b = ((const float4*)x)[2 * i + 1];
        float vv[8] = {a.x, a.y, a.z, a.w, b.x, b.y, b.z, b.w};
        short8 h, l;
#pragma unroll
        for (int k = 0; k < 8; ++k) {
            __hip_bfloat16 hb = __float2bfloat16(vv[k]);
            float hf = __bfloat162float(hb);
            __hip_bfloat16 lb = __float2bfloat16(vv[k] - hf);
            h[k] = *(short*)&hb;
            l[k] = *(short*)&lb;
        }
        ((short8*)xhi)[i] = h;
        ((short8*)xlo)[i] = l;
    }
}

// ---------------------------------------------------------------------------
// Kernel 2: per output row o (group g = o/128, block r = o/32):
//   Wm = exp(W) on diag block, W on strict-lower; norm over active K;
//   Wn = exp(ls)*Wm/norm -> bf16 hi/lo, packed triangular, zero-padded to
//   kpad=(g+1)*128; log of diag 32x32 block -> jac (separate 32-thread pass).
// ---------------------------------------------------------------------------
__global__ __launch_bounds__(256) void prep_w(const float* __restrict__ W,
                                              const float* __restrict__ wls,
                                              u16* __restrict__ bhi,
                                              u16* __restrict__ blo,
                                              float* __restrict__ jac)
{
    const int o    = 4095 - blockIdx.x;   // heavy rows first (LPT)
    const int r    = o >> 5;              // 32-block row index
    const int g    = o >> 7;              // 128-group index (= GEMM N-tile j)
    const int kact = (r + 1) * 32;        // active K for this row
    const int kpad = (g + 1) << 7;        // packed row length
    const int dlo  = r * 32;              // diag block col start

    __shared__ float rowbuf[4096];
    __shared__ float red[4];

    // pass 1: masked transform + sum of squares (f32x4 in, f32x4 LDS out)
    const float* wrow = W + (size_t)o * IN_FEAT;
    float ss = 0.f;
    const int k4 = kact >> 2;
    for (int c4 = threadIdx.x; c4 < k4; c4 += 256) {
        float4 wv = ((const float4*)wrow)[c4];
        f32x4 out;
        float vv[4] = {wv.x, wv.y, wv.z, wv.w};
        const int c = c4 * 4;
#pragma unroll
        for (int e = 0; e < 4; ++e) {
            float wm = (c + e >= dlo) ? __expf(vv[e]) : vv[e];
            out[e] = wm;
            ss += wm * wm;
        }
        *(f32x4*)&rowbuf[c] = out;
    }
    for (int off = 32; off > 0; off >>= 1) ss += __shfl_down(ss, off, 64);
    const int lane = threadIdx.x & 63, wid = threadIdx.x >> 6;
    if (lane == 0) red[wid] = ss;
    __syncthreads();
    const float total = red[0] + red[1] + red[2] + red[3];
    const float scale = expf(wls[o]) / sqrtf(total);

    // pass 2: scale + bf16 hi/lo split, 16B stores, packed layout
    const size_t rowbase = (size_t)16384 * ((size_t)g * (g + 1) / 2)
                         + (size_t)(o & 127) * kpad;
    u16* bh = bhi + rowbase;
    u16* bl = blo + rowbase;
    for (int c0 = threadIdx.x * 8; c0 < kpad; c0 += 2048) {
        short8 hv, lv;
        if (c0 + 8 <= kact) {
            f32x4 w0 = *(const f32x4*)&rowbuf[c0];
            f32x4 w1 = *(const f32x4*)&rowbuf[c0 + 4];
            float vv[8] = {w0[0], w0[1], w0[2], w0[3],
                           w1[0], w1[1], w1[2], w1[3]};
#pragma unroll
            for (int e = 0; e < 8; ++e) {
                float wn = vv[e] * scale;
                __hip_bfloat16 h = __float2bfloat16(wn);
                float hf = __bfloat162float(h);
                __hip_bfloat16 l = __float2bfloat16(wn - hf);
                hv[e] = *(short*)&h;
                lv[e] = *(short*)&l;
            }
        } else {
#pragma unroll
            for (int e = 0; e < 8; ++e) {
                const int c = c0 + e;
                float wn = (c < kact) ? rowbuf[c] * scale : 0.f;
                __hip_bfloat16 h = __float2bfloat16(wn);
                float hf = __bfloat162float(h);
                __hip_bfloat16 l = __float2bfloat16(wn - hf);
                hv[e] = *(short*)&h;
                lv[e] = *(short*)&l;
            }
        }
        *(short8*)(bh + c0) = hv;
        *(short8*)(bl + c0) = lv;
    }

    // pass 3: jac = log(diag 32 window), one thread per column
    if (threadIdx.x < 32)
        jac[(size_t)r * 1024 + (size_t)(o & 31) * 32 + threadIdx.x] =
            __logf(rowbuf[dlo + threadIdx.x] * scale);
}

// ---------------------------------------------------------------------------
// Kernel 3: y[b,o] = sum_k x[b,k]*Wn[o,k] + bias[o]  (NT GEMM, bf16x3 split)
// 128x128 tile, BK=32, 4 waves in 2x2 (64x64 each), mfma_f32_32x32x16_bf16
// (R7: switched from 16x16x32 — 2382 vs 2075 TF ubench, half the MFMA
// instruction count). Per wave: 2x2 accs of 32x32, 2 k-chunks, 3 terms
// = 24 MFMA / K-step, ordered term-outermost (dep distance 4).
// 2-PHASE double-buffered pipeline (T3 minimum). Measured R5/R6 at 16x16:
// 128 us, MfmaUtil 35%, conflicts 0.
//
// LDS swizzle (rule #21; verified SQ_LDS_BANK_CONFLICT = 0):
//   slot (row, s) holds k-group s ^ ((row>>1)&3); write side via pre-swizzled
//   global col-group (l&3)^((l>>3)&3); read side slot = q ^ ((row>>1)&3).
//   32x32 read (row=lane&31, q = kc*2+(lane>>5)): per b128 phase
//   (16 lanes, rows 0-15) quads (4*row+slot)%8 cover all 8 -> 2-way, free.
// ---------------------------------------------------------------------------
__global__ __launch_bounds__(256, 2) void gemm_bar(
    const u16* __restrict__ xhi, const u16* __restrict__ xlo,
    const u16* __restrict__ bhi, const u16* __restrict__ blo,
    const float* __restrict__ bias, float* __restrict__ y)
{
    __shared__ __align__(16) u16 As_hi[2][128][32];
    __shared__ __align__(16) u16 As_lo[2][128][32];
    __shared__ __align__(16) u16 Bs_hi[2][128][32];
    __shared__ __align__(16) u16 Bs_lo[2][128][32];

    // Heavy-tiles-first dispatch; pair (bid, bid+256) lands on same CU and
    // sums to 33 K-units (balanced).
    const int bid = blockIdx.x;          // 0..511
    const int jj  = bid >> 4;            // 0..31
    const int j   = (jj < 16) ? (31 - jj) : (jj - 16);
    const int i   = bid & 15;
    const int bm0 = i * 128;
    const int bn0 = j * 128;
    const int ksteps = (j + 1) * 4;      // K = (j+1)*128, BK=32

    const int tid  = threadIdx.x;
    const int w    = tid >> 6;
    const int lane = tid & 63;
    const int wm   = (w & 1) * 64;       // wave's M offset in tile
    const int wn   = (w >> 1) * 64;      // wave's N offset in tile
    const int frow = lane & 31;          // fragment row within 32-tile
    const int kg   = lane >> 5;          // k half-group (0/1) within chunk
    const int sw   = (lane >> 1) & 3;    // row-dependent swizzle key
    const int ks0  = ((0 + kg) ^ sw) * 8;   // kc=0 swizzled col offset (u16)
    const int ks1  = ((2 + kg) ^ sw) * 8;   // kc=1 swizzled col offset (u16)
    const int srr  = lane >> 2;                              // staging row in 16-chunk
    const int scb  = ((lane & 3) ^ ((lane >> 3) & 3)) * 8;   // pre-swz src col (u16)

    // staging assignment per wave (each wave owns one of the 4 tiles)
    const u16* gbase;     // tile row 0 in global
    size_t gstride;       // u16 per row
    u16* ldst0;           // buffer-0 LDS base for this wave
    if (w == 0) {
        gbase = xhi + (size_t)bm0 * IN_FEAT; gstride = IN_FEAT;
        ldst0 = &As_hi[0][0][0];
    } else if (w == 1) {
        gbase = xlo + (size_t)bm0 * IN_FEAT; gstride = IN_FEAT;
        ldst0 = &As_lo[0][0][0];
    } else {
        const size_t pbase = (size_t)16384 * ((size_t)j * (j + 1) / 2);
        gstride = (size_t)ksteps * 32;
        if (w == 2) { gbase = bhi + pbase; ldst0 = &Bs_hi[0][0][0]; }
        else        { gbase = blo + pbase; ldst0 = &Bs_lo[0][0][0]; }
    }

    f32x16 acc[2][2];
#pragma unroll
    for (int a = 0; a < 2; ++a)
#pragma unroll
        for (int b = 0; b < 2; ++b)
#pragma unroll
            for (int e = 0; e < 16; ++e)
                acc[a][b][e] = 0.f;

#define STAGE(buf, kt)                                                         \
    do {                                                                       \
        const int _kb = (kt) * 32;                                             \
        u16* _dst = ldst0 + (buf) * 4096;                                      \
        _Pragma("unroll")                                                      \
        for (int _t = 0; _t < 8; ++_t) {                                       \
            const u16* _g = gbase + (size_t)(_t * 16 + srr) * gstride          \
                                  + _kb + scb;                                 \
            GLOAD16(_g, _dst + _t * 512);                                      \
        }                                                                      \
    } while (0)

    STAGE(0, 0);
    __syncthreads();                     // buf0 staged (vmcnt(0) drain)

    int cur = 0;
    for (int kt = 0; kt < ksteps; ++kt) {
        if (kt + 1 < ksteps) STAGE(cur ^ 1, kt + 1);   // prefetch next step

        const int cb = cur * 4096;       // u16 offset of current buffer
#pragma unroll
        for (int kc = 0; kc < 2; ++kc) {
            const int ks = kc ? ks1 : ks0;
            short8 ah[2], al[2], bh[2], bl[2];
#pragma unroll
            for (int mi = 0; mi < 2; ++mi) {
                const int row = wm + mi * 32 + frow;
                ah[mi] = *(const short8*)(&As_hi[0][0][0] + cb + row * 32 + ks);
                al[mi] = *(const short8*)(&As_lo[0][0][0] + cb + row * 32 + ks);
            }
#pragma unroll
            for (int ni = 0; ni < 2; ++ni) {
                const int row = wn + ni * 32 + frow;
                bh[ni] = *(const short8*)(&Bs_hi[0][0][0] + cb + row * 32 + ks);
                bl[ni] = *(const short8*)(&Bs_lo[0][0][0] + cb + row * 32 + ks);
            }
            // term-outermost: dependent writes to same acc are 4 apart
#pragma unroll
            for (int mi = 0; mi < 2; ++mi)
#pragma unroll
                for (int ni = 0; ni < 2; ++ni)
                    acc[mi][ni] = __builtin_amdgcn_mfma_f32_32x32x16_bf16(
                        ah[mi], bh[ni], acc[mi][ni], 0, 0, 0);
#pragma unroll
            for (int mi = 0; mi < 2; ++mi)
#pragma unroll
                for (int ni = 0; ni < 2; ++ni)
                    acc[mi][ni] = __builtin_amdgcn_mfma_f32_32x32x16_bf16(
                        ah[mi], bl[ni], acc[mi][ni], 0, 0, 0);
#pragma unroll
            for (int mi = 0; mi < 2; ++mi)
#pragma unroll
                for (int ni = 0; ni < 2; ++ni)
                    acc[mi][ni] = __builtin_amdgcn_mfma_f32_32x32x16_bf16(
                        al[mi], bh[ni], acc[mi][ni], 0, 0, 0);
        }
        __syncthreads();   // drains this wave's stage (vmcnt(0)) + ds_reads
        cur ^= 1;
    }
#undef STAGE

    // epilogue: 32x32 C/D layout (m74/m101-verified):
    //   col = lane&31 (B-side n), row = (reg&3) + 8*(reg>>2) + 4*(lane>>5)
    const int rbase = 4 * (lane >> 5);
#pragma unroll
    for (int ni = 0; ni < 2; ++ni) {
        const int n = bn0 + wn + ni * 32 + (lane & 31);
        const float bv = bias[n];
#pragma unroll
        for (int mi = 0; mi < 2; ++mi) {
            const int mb = bm0 + wm + mi * 32 + rbase;
#pragma unroll
            for (int reg = 0; reg < 16; ++reg) {
                const int m = mb + (reg & 3) + 8 * (reg >> 2);
                y[(size_t)m * 4096 + n] = acc[mi][ni][reg] + bv;
            }
        }
    }
}

// ---------------------------------------------------------------------------
extern "C" void kernel_launch(void* const* d_in, const int* in_sizes, int n_in,
                              void* d_out, int out_size, void* d_ws, size_t ws_size,
                              hipStream_t stream)
{
    const float* x    = (const float*)d_in[0];
    const float* W    = (const float*)d_in[1];
    const float* bias = (const float*)d_in[2];
    const float* wls  = (const float*)d_in[3];
    // d_in[4], d_in[5] (masks) are not read: mask structure derived from indices.

    // workspace layout: packed-B hi/lo (2 x 16.5 MiB) + X hi/lo (2 x 16 MiB)
    const size_t need = ((size_t)BPACK * 2 + (size_t)BATCH * IN_FEAT * 2)
                        * sizeof(u16);   // 68,157,440 B
    if (ws_size < need) return;  // clean failure signal (output stays poisoned)

    u16* Bhi = (u16*)d_ws;
    u16* Blo = Bhi + (size_t)BPACK;
    u16* Xhi = Blo + (size_t)BPACK;
    u16* Xlo = Xhi + (size_t)BATCH * IN_FEAT;

    float* y   = (float*)d_out;
    float* jac = y + (size_t)BATCH * OUT_FEAT;   // 128*32*32 floats

    split_x<<<1024, 256, 0, stream>>>(x, Xhi, Xlo);
    prep_w<<<4096, 256, 0, stream>>>(W, wls, Bhi, Blo, jac);
    gemm_bar<<<512, 256, 0, stream>>>(Xhi, Xlo, Bhi, Blo, bias, y);
}

// Round 8
// 298.720 us; speedup vs baseline: 1.0541x; 1.0541x over previous
//
#include <hip/hip_runtime.h>
#include <hip/hip_bf16.h>

typedef unsigned short u16;
using short8 = __attribute__((ext_vector_type(8))) short;
using f32x4  = __attribute__((ext_vector_type(4))) float;

#define IN_FEAT  4096
#define OUT_FEAT 4096
#define BATCH    2048
// packed triangular B: group g (128 rows) has row length (g+1)*128 u16;
// group base = 16384 * g*(g+1)/2; total = 16384 * 528 u16 per matrix.
#define BPACK    8650752

// direct global->LDS, 16B per lane; LDS dest is wave-uniform base + lane*16
#define GLOAD16(gp, lp)                                                        \
    __builtin_amdgcn_global_load_lds(                                          \
        (__attribute__((address_space(1))) void*)(gp),                         \
        (__attribute__((address_space(3))) void*)(lp), 16, 0, 0)

// ---------------------------------------------------------------------------
// Kernel 1: split x (f32) into bf16 hi + lo residual. 16B/lane both ways.
// ---------------------------------------------------------------------------
__global__ __launch_bounds__(256) void split_x(const float* __restrict__ x,
                                               u16* __restrict__ xhi,
                                               u16* __restrict__ xlo)
{
    const int n8 = (BATCH * IN_FEAT) / 8;
    for (int i = blockIdx.x * blockDim.x + threadIdx.x; i < n8;
         i += gridDim.x * blockDim.x) {
        float4 a = ((const float4*)x)[2 * i];
        float4 b = ((const float4*)x)[2 * i + 1];
        float vv[8] = {a.x, a.y, a.z, a.w, b.x, b.y, b.z, b.w};
        short8 h, l;
#pragma unroll
        for (int k = 0; k < 8; ++k) {
            __hip_bfloat16 hb = __float2bfloat16(vv[k]);
            float hf = __bfloat162float(hb);
            __hip_bfloat16 lb = __float2bfloat16(vv[k] - hf);
            h[k] = *(short*)&hb;
            l[k] = *(short*)&lb;
        }
        ((short8*)xhi)[i] = h;
        ((short8*)xlo)[i] = l;
    }
}

// ---------------------------------------------------------------------------
// Kernel 2: per output row o (group g = o/128, block r = o/32):
//   Wm = exp(W) on diag block, W on strict-lower; norm over active K;
//   Wn = exp(ls)*Wm/norm -> bf16 hi/lo, packed triangular, zero-padded to
//   kpad=(g+1)*128; log of diag 32x32 block -> jac (separate 32-thread pass).
// ---------------------------------------------------------------------------
__global__ __launch_bounds__(256) void prep_w(const float* __restrict__ W,
                                              const float* __restrict__ wls,
                                              u16* __restrict__ bhi,
                                              u16* __restrict__ blo,
                                              float* __restrict__ jac)
{
    const int o    = 4095 - blockIdx.x;   // heavy rows first (LPT)
    const int r    = o >> 5;              // 32-block row index
    const int g    = o >> 7;              // 128-group index (= GEMM N-tile j)
    const int kact = (r + 1) * 32;        // active K for this row
    const int kpad = (g + 1) << 7;        // packed row length
    const int dlo  = r * 32;              // diag block col start

    __shared__ float rowbuf[4096];
    __shared__ float red[4];

    // pass 1: masked transform + sum of squares (f32x4 in, f32x4 LDS out)
    const float* wrow = W + (size_t)o * IN_FEAT;
    float ss = 0.f;
    const int k4 = kact >> 2;
    for (int c4 = threadIdx.x; c4 < k4; c4 += 256) {
        float4 wv = ((const float4*)wrow)[c4];
        f32x4 out;
        float vv[4] = {wv.x, wv.y, wv.z, wv.w};
        const int c = c4 * 4;
#pragma unroll
        for (int e = 0; e < 4; ++e) {
            float wm = (c + e >= dlo) ? __expf(vv[e]) : vv[e];
            out[e] = wm;
            ss += wm * wm;
        }
        *(f32x4*)&rowbuf[c] = out;
    }
    for (int off = 32; off > 0; off >>= 1) ss += __shfl_down(ss, off, 64);
    const int lane = threadIdx.x & 63, wid = threadIdx.x >> 6;
    if (lane == 0) red[wid] = ss;
    __syncthreads();
    const float total = red[0] + red[1] + red[2] + red[3];
    const float scale = expf(wls[o]) / sqrtf(total);

    // pass 2: scale + bf16 hi/lo split, 16B stores, packed layout
    const size_t rowbase = (size_t)16384 * ((size_t)g * (g + 1) / 2)
                         + (size_t)(o & 127) * kpad;
    u16* bh = bhi + rowbase;
    u16* bl = blo + rowbase;
    for (int c0 = threadIdx.x * 8; c0 < kpad; c0 += 2048) {
        short8 hv, lv;
        if (c0 + 8 <= kact) {
            f32x4 w0 = *(const f32x4*)&rowbuf[c0];
            f32x4 w1 = *(const f32x4*)&rowbuf[c0 + 4];
            float vv[8] = {w0[0], w0[1], w0[2], w0[3],
                           w1[0], w1[1], w1[2], w1[3]};
#pragma unroll
            for (int e = 0; e < 8; ++e) {
                float wn = vv[e] * scale;
                __hip_bfloat16 h = __float2bfloat16(wn);
                float hf = __bfloat162float(h);
                __hip_bfloat16 l = __float2bfloat16(wn - hf);
                hv[e] = *(short*)&h;
                lv[e] = *(short*)&l;
            }
        } else {
#pragma unroll
            for (int e = 0; e < 8; ++e) {
                const int c = c0 + e;
                float wn = (c < kact) ? rowbuf[c] * scale : 0.f;
                __hip_bfloat16 h = __float2bfloat16(wn);
                float hf = __bfloat162float(h);
                __hip_bfloat16 l = __float2bfloat16(wn - hf);
                hv[e] = *(short*)&h;
                lv[e] = *(short*)&l;
            }
        }
        *(short8*)(bh + c0) = hv;
        *(short8*)(bl + c0) = lv;
    }

    // pass 3: jac = log(diag 32 window), one thread per column
    if (threadIdx.x < 32)
        jac[(size_t)r * 1024 + (size_t)(o & 31) * 32 + threadIdx.x] =
            __logf(rowbuf[dlo + threadIdx.x] * scale);
}

// ---------------------------------------------------------------------------
// Kernel 3: y[b,o] = sum_k x[b,k]*Wn[o,k] + bias[o]  (NT GEMM, bf16x3 split)
// 128x128 tile, BK=32, 4 waves in 2x2 (64x64 each), mfma_f32_16x16x32_bf16
// (REVERTED from 32x32: R7 measured exactly +4 conflict-cycles/ds_read_b128;
// the 16x16 pattern is the validated conflict-free one, R5/R6 = 0).
//
// R8: T4 counted-vmcnt pipeline — 3-deep LDS ring, ONE s_barrier per K-step,
// vmcnt(8) in steady state (stage kt+1's 8 loads stay in flight ACROSS the
// barrier; never drain to 0 until the last step). WAR-safe: STAGE(kt+2) is
// issued after the barrier that every wave reaches only once its reads of
// buf[(kt+2)%3] (done in iter kt-1) have retired (lgkmcnt before MFMA use).
// Cost: 96KB LDS -> 1 block/CU; grid is pure LPT (heavy j first, backfill).
//
// LDS swizzle (rule #21; verified SQ_LDS_BANK_CONFLICT = 0 in R5/R6):
//   slot (row, s) holds k-group s ^ ((row>>1)&3); write side via pre-swizzled
//   global col-group (l&3)^((l>>3)&3); read side slot = kq ^ ((fr>>1)&3).
// ---------------------------------------------------------------------------
__global__ __launch_bounds__(256, 1) void gemm_bar(
    const u16* __restrict__ xhi, const u16* __restrict__ xlo,
    const u16* __restrict__ bhi, const u16* __restrict__ blo,
    const float* __restrict__ bias, float* __restrict__ y)
{
    __shared__ __align__(16) u16 As_hi[3][128][32];
    __shared__ __align__(16) u16 As_lo[3][128][32];
    __shared__ __align__(16) u16 Bs_hi[3][128][32];
    __shared__ __align__(16) u16 Bs_lo[3][128][32];

    // Pure LPT: heavy tiles (j=31) dispatched first, short ones backfill.
    const int bid = blockIdx.x;          // 0..511
    const int j   = 31 - (bid >> 4);
    const int i   = bid & 15;
    const int bm0 = i * 128;
    const int bn0 = j * 128;
    const int ksteps = (j + 1) * 4;      // K = (j+1)*128, BK=32  (>= 4)

    const int tid  = threadIdx.x;
    const int w    = tid >> 6;
    const int lane = tid & 63;
    const int wm   = (w & 1) * 64;       // wave's M offset in tile
    const int wn   = (w >> 1) * 64;      // wave's N offset in tile
    const int fr   = lane & 15;          // fragment row
    const int kq   = lane >> 4;          // fragment k-group (0..3)
    const int kcg  = (kq ^ ((fr >> 1) & 3)) * 8;             // swizzled read col (u16)
    const int srr  = lane >> 2;                              // staging row in 16-chunk
    const int scb  = ((lane & 3) ^ ((lane >> 3) & 3)) * 8;   // pre-swz src col (u16)

    // staging assignment per wave (each wave owns one of the 4 tiles)
    const u16* gbase;     // tile row 0 in global
    size_t gstride;       // u16 per row
    u16* ldst0;           // ring-buffer-0 LDS base for this wave
    if (w == 0) {
        gbase = xhi + (size_t)bm0 * IN_FEAT; gstride = IN_FEAT;
        ldst0 = &As_hi[0][0][0];
    } else if (w == 1) {
        gbase = xlo + (size_t)bm0 * IN_FEAT; gstride = IN_FEAT;
        ldst0 = &As_lo[0][0][0];
    } else {
        const size_t pbase = (size_t)16384 * ((size_t)j * (j + 1) / 2);
        gstride = (size_t)ksteps * 32;
        if (w == 2) { gbase = bhi + pbase; ldst0 = &Bs_hi[0][0][0]; }
        else        { gbase = blo + pbase; ldst0 = &Bs_lo[0][0][0]; }
    }

    f32x4 acc[4][4];
#pragma unroll
    for (int a = 0; a < 4; ++a)
#pragma unroll
        for (int b = 0; b < 4; ++b)
            acc[a][b] = (f32x4){0.f, 0.f, 0.f, 0.f};

#define STAGE(buf, kt)                                                         \
    do {                                                                       \
        const int _kb = (kt) * 32;                                             \
        u16* _dst = ldst0 + (buf) * 4096;                                      \
        _Pragma("unroll")                                                      \
        for (int _t = 0; _t < 8; ++_t) {                                       \
            const u16* _g = gbase + (size_t)(_t * 16 + srr) * gstride          \
                                  + _kb + scb;                                 \
            GLOAD16(_g, _dst + _t * 512);                                      \
        }                                                                      \
    } while (0)

    // prologue: 2 stages in flight before first consume
    STAGE(0, 0);
    STAGE(1, 1);

    int rb = 0;                          // ring slot of current K-step
    for (int kt = 0; kt < ksteps; ++kt) {
        // retire ONLY the oldest stage (kt); stage kt+1 stays in flight
        if (kt + 1 < ksteps) {
            asm volatile("s_waitcnt vmcnt(8)" ::: "memory");
        } else {
            asm volatile("s_waitcnt vmcnt(0)" ::: "memory");
        }
        __builtin_amdgcn_sched_barrier(0);
        __builtin_amdgcn_s_barrier();      // all waves: buf[kt] staged
        __builtin_amdgcn_sched_barrier(0);

        if (kt + 2 < ksteps) {             // prefetch 2 ahead into freed slot
            int sb = rb - 1; if (sb < 0) sb += 3;   // (kt+2)%3
            STAGE(sb, kt + 2);
        }

        const int cb = rb * 4096;          // u16 offset of current ring slot
        short8 ah[4], al[4], bh[4], bl[4];
#pragma unroll
        for (int mi = 0; mi < 4; ++mi) {
            const int row = wm + mi * 16 + fr;
            ah[mi] = *(const short8*)(&As_hi[0][0][0] + cb + row * 32 + kcg);
            al[mi] = *(const short8*)(&As_lo[0][0][0] + cb + row * 32 + kcg);
        }
#pragma unroll
        for (int ni = 0; ni < 4; ++ni) {
            const int row = wn + ni * 16 + fr;
            bh[ni] = *(const short8*)(&Bs_hi[0][0][0] + cb + row * 32 + kcg);
            bl[ni] = *(const short8*)(&Bs_lo[0][0][0] + cb + row * 32 + kcg);
        }
#pragma unroll
        for (int mi = 0; mi < 4; ++mi)
#pragma unroll
            for (int ni = 0; ni < 4; ++ni) {
                f32x4 c = acc[mi][ni];
                c = __builtin_amdgcn_mfma_f32_16x16x32_bf16(ah[mi], bh[ni], c, 0, 0, 0);
                c = __builtin_amdgcn_mfma_f32_16x16x32_bf16(ah[mi], bl[ni], c, 0, 0, 0);
                c = __builtin_amdgcn_mfma_f32_16x16x32_bf16(al[mi], bh[ni], c, 0, 0, 0);
                acc[mi][ni] = c;
            }

        rb = (rb == 2) ? 0 : rb + 1;
    }
#undef STAGE

    // epilogue: C/D layout col=lane&15 (B-side n), row=(lane>>4)*4+q (A-side m)
    const int crow = (lane >> 4) * 4;
    const int ccol = lane & 15;
#pragma unroll
    for (int ni = 0; ni < 4; ++ni) {
        const int n = bn0 + wn + ni * 16 + ccol;
        const float bv = bias[n];
#pragma unroll
        for (int mi = 0; mi < 4; ++mi) {
#pragma unroll
            for (int q = 0; q < 4; ++q) {
                const int m = bm0 + wm + mi * 16 + crow + q;
                y[(size_t)m * 4096 + n] = acc[mi][ni][q] + bv;
            }
        }
    }
}

// ---------------------------------------------------------------------------
extern "C" void kernel_launch(void* const* d_in, const int* in_sizes, int n_in,
                              void* d_out, int out_size, void* d_ws, size_t ws_size,
                              hipStream_t stream)
{
    const float* x    = (const float*)d_in[0];
    const float* W    = (const float*)d_in[1];
    const float* bias = (const float*)d_in[2];
    const float* wls  = (const float*)d_in[3];
    // d_in[4], d_in[5] (masks) are not read: mask structure derived from indices.

    // workspace layout: packed-B hi/lo (2 x 16.5 MiB) + X hi/lo (2 x 16 MiB)
    const size_t need = ((size_t)BPACK * 2 + (size_t)BATCH * IN_FEAT * 2)
                        * sizeof(u16);   // 68,157,440 B
    if (ws_size < need) return;  // clean failure signal (output stays poisoned)

    u16* Bhi = (u16*)d_ws;
    u16* Blo = Bhi + (size_t)BPACK;
    u16* Xhi = Blo + (size_t)BPACK;
    u16* Xlo = Xhi + (size_t)BATCH * IN_FEAT;

    float* y   = (float*)d_out;
    float* jac = y + (size_t)BATCH * OUT_FEAT;   // 128*32*32 floats

    split_x<<<1024, 256, 0, stream>>>(x, Xhi, Xlo);
    prep_w<<<4096, 256, 0, stream>>>(W, wls, Bhi, Blo, jac);
    gemm_bar<<<512, 256, 0, stream>>>(Xhi, Xlo, Bhi, Blo, bias, y);
}